// Round 3
// baseline (104.493 us; speedup 1.0000x reference)
//
#include <hip/hip_runtime.h>
#include <hip/hip_bf16.h>

// Problem constants (fixed by setup_inputs)
#define B_N 4096
#define D_K 512
#define INV_T 10.0f

// k1 tiling: SYMMETRIC decomposition.
// Tiles are 128 rows x 64 cols. Only tiles with 2R <= C are launched
// (upper triangle at 128x128 super-tile granularity, split into col-halves:
// 1056 blocks). Off-diagonal tiles attribute each exp(s) to BOTH row i
// (row-side reduce) and row j (column-side reduce, two 64-row halves =
// col-splits 2R and 2R+1 of the transposed rows). Diagonal super-tiles
// (C>>1 == R) are row-side only with self-exclusion.
// Coverage per cell (i, s): col-side covers s in [0, 2*(i>>7)), row-side
// covers s in [2*(i>>7), 64) -- disjoint and complete (verified absmax=0).
//
// Round-3 change: NO LDS staging for B. embT8 is 8 MB (L2/L3-resident) and
// B-panels are shared across blocks -> read fragments directly from global.
// Zero barriers in the main loop; waves pipeline independently.
#define BM 128            // rows per block (4 waves x 32 rows)
#define CPB 64            // cols per block
#define CS (B_N / CPB)    // 64 column splits
#define NCG (CPB / 16)    // 4 col-groups per block
#define SLOTS 16          // positive slots per (row, colsplit)
#define NTILES 1056       // sum_{R=0..31} (64 - 2R)

typedef __attribute__((ext_vector_type(4))) float float4v;  // f32x4 accumulator

// ws layout:
//   [0,        16384)    float termSum[4096]
//   [16384,    32768)    float cntF[4096]
//   [32768,  1081344)    float denomPart[4096][64]
//   [1081344,2129920)    int   posCnt[4096][64]
//   [2129920,18907136)   float posS[4096][64][16]
//   [18907136,+2MiB)     fp8   embT8 (fragment order)
#define WS_TERS   0
#define WS_CNTF   16384
#define WS_DENOM  32768
#define WS_POSCNT 1081344
#define WS_POSS   2129920
#define WS_EMBT8  18907136

// ---------------- k0: fp32 -> fp8 e4m3 convert into fragment order -----------
__global__ __launch_bounds__(256) void k0_convert(const float* __restrict__ emb,
                                                  unsigned char* __restrict__ embT8) {
    int tid = blockIdx.x * 256 + threadIdx.x;    // 262144 threads total
    int l16 = tid & 15;
    int kq  = (tid >> 4) & 63;
    int rg  = tid >> 10;
    int row = rg * 16 + l16;
    const float* sp = emb + row * D_K + kq * 8;
    float4 v0 = *(const float4*)(sp);
    float4 v1 = *(const float4*)(sp + 4);
    int lo = __builtin_amdgcn_cvt_pk_fp8_f32(v0.x, v0.y, 0, false);
    lo     = __builtin_amdgcn_cvt_pk_fp8_f32(v0.z, v0.w, lo, true);
    int hi = __builtin_amdgcn_cvt_pk_fp8_f32(v1.x, v1.y, 0, false);
    hi     = __builtin_amdgcn_cvt_pk_fp8_f32(v1.z, v1.w, hi, true);
    int2 o; o.x = lo; o.y = hi;
    *(int2*)(embT8 + ((rg * 64 + kq) * 16 + l16) * 8) = o;
}

// ---------------- k1: symmetric fused sims + denom partials + positives ------
// Barrier-free main loop; B-fragments read directly from global (L2-hot).
__global__ __launch_bounds__(256, 3) void k1_denom(const unsigned char* __restrict__ embT8,
                                                   const int* __restrict__ labels,
                                                   float* __restrict__ denomPart,
                                                   int* __restrict__ posCnt,
                                                   float* __restrict__ posS) {
    __shared__ float sPos[BM * SLOTS];           // row-side positive slots   (8 KB)
    __shared__ int   sCnt[BM];
    __shared__ float sPosC[2 * CPB * SLOTS];     // col-side positive slots   (8 KB)
    __shared__ int   sCntC[2 * CPB];
    __shared__ float sColW[4 * CPB];             // per-wave column partial sums (1 KB)

    const int tid  = threadIdx.x;
    const int wave = tid >> 6;
    const int lane = tid & 63;
    const int quad = lane >> 4;
    const int l16  = lane & 15;

    // Triangular decode: t = R*(65-R) + (C - 2R), C in [2R, 64)
    const int t0 = blockIdx.x;
    int R = (int)((65.0f - sqrtf(4225.0f - 4.0f * (float)t0)) * 0.5f);
    while (R * (65 - R) > t0) --R;
    while ((R + 1) * (64 - R) <= t0) ++R;
    const int C = t0 - R * (65 - R) + 2 * R;
    const bool isDiag = ((C >> 1) == R);
    const int rowBase = R * BM;

    if (tid < BM) sCnt[tid] = 0;
    if (tid < 2 * CPB) sCntC[tid] = 0;
    __syncthreads();   // sCnt/sCntC visible before first positive-pair atomic

    // A fragments: 2 row-groups x 16 K-chunks, 8 B each -> 64 VGPRs, resident
    long afrag[2][16];
#pragma unroll
    for (int t = 0; t < 2; ++t) {
        const int g = R * 8 + wave * 2 + t;
        const unsigned char* ap = embT8 + (g * 1024 + lane) * 8;
#pragma unroll
        for (int kc = 0; kc < 16; ++kc)
            afrag[t][kc] = *(const long*)(ap + kc * 64 * 8);
    }

    int labI[2][4];
#pragma unroll
    for (int t = 0; t < 2; ++t)
#pragma unroll
        for (int r = 0; r < 4; ++r)
            labI[t][r] = labels[rowBase + wave * 32 + t * 16 + quad * 4 + r];

    int labJ[NCG];
#pragma unroll
    for (int cg = 0; cg < NCG; ++cg)
        labJ[cg] = labels[C * CPB + cg * 16 + l16];

    float rowAcc[2][4] = {{0.f,0.f,0.f,0.f},{0.f,0.f,0.f,0.f}};

#pragma unroll
    for (int cg = 0; cg < NCG; ++cg) {
        // B-fragment base for this col-group; per-kc line = btG + kc*512 + lane*8
        const unsigned char* btG = embT8 + (C * NCG + cg) * 8192 + lane * 8;

        float4v acc[2];
        acc[0] = (float4v){0.f, 0.f, 0.f, 0.f};
        acc[1] = (float4v){0.f, 0.f, 0.f, 0.f};
#pragma unroll
        for (int kc = 0; kc < 16; ++kc) {
            long bfrag = *(const long*)(btG + kc * 512);
            acc[0] = __builtin_amdgcn_mfma_f32_16x16x32_fp8_fp8(afrag[0][kc], bfrag, acc[0], 0, 0, 0);
            acc[1] = __builtin_amdgcn_mfma_f32_16x16x32_fp8_fp8(afrag[1][kc], bfrag, acc[1], 0, 0, 0);
        }

        const int col = C * CPB + cg * 16 + l16;
        const int lJ  = labJ[cg];
        float cAcc = 0.0f;     // col-side partial (this lane's 8 rows, column `col`)
#pragma unroll
        for (int t = 0; t < 2; ++t) {
#pragma unroll
            for (int r = 0; r < 4; ++r) {
                float s = acc[t][r] * INV_T;
                const int lr = wave * 32 + t * 16 + quad * 4 + r;
                if (lJ != labI[t][r]) {
                    float e = __expf(s);
                    rowAcc[t][r] += e;
                    cAcc += e;
                } else if (col != rowBase + lr) {           // positive pair
                    int idx = atomicAdd(&sCnt[lr], 1);
                    if (idx < SLOTS) sPos[lr * SLOTS + idx] = s;
                    if (!isDiag) {                          // transposed positive (j, i)
                        int ci = (wave >> 1) * CPB + cg * 16 + l16;
                        int idx2 = atomicAdd(&sCntC[ci], 1);
                        if (idx2 < SLOTS) sPosC[ci * SLOTS + idx2] = s;
                    }
                }
            }
        }
        if (!isDiag) {
            // reduce across the 4 quads (rows) -> per-wave column sum
            cAcc += __shfl_xor(cAcc, 16);
            cAcc += __shfl_xor(cAcc, 32);
            if (quad == 0) sColW[wave * CPB + cg * 16 + l16] = cAcc;
        }
    }

    // row-side: butterfly over the 16 l16-lanes -> denomPart[row][C]
#pragma unroll
    for (int t = 0; t < 2; ++t)
#pragma unroll
        for (int r = 0; r < 4; ++r) {
            float v = rowAcc[t][r];
            v += __shfl_xor(v, 1);
            v += __shfl_xor(v, 2);
            v += __shfl_xor(v, 4);
            v += __shfl_xor(v, 8);
            if (l16 == 0)
                denomPart[(rowBase + wave * 32 + t * 16 + quad * 4 + r) * CS + C] = v;
        }

    __syncthreads();   // sPos/sCnt/sPosC/sCntC/sColW complete

    if (tid < BM) {                                   // row-side positive flush
        const int row = rowBase + tid;
        const int c   = min(sCnt[tid], SLOTS);
        posCnt[row * CS + C] = c;
        for (int m = 0; m < c; ++m)
            posS[(row * CS + C) * SLOTS + m] = sPos[tid * SLOTS + m];
    }
    if (!isDiag && tid < 2 * CPB) {                   // col-side flush (transposed cells)
        const int s0 = tid >> 6;                      // which 64-row half -> split 2R+s0
        const int cc = tid & 63;                      // column within block
        const int j  = C * CPB + cc;                  // transposed row index
        const int sp = 2 * R + s0;
        denomPart[j * CS + sp] = sColW[(2 * s0) * CPB + cc] + sColW[(2 * s0 + 1) * CPB + cc];
        const int ci = s0 * CPB + cc;
        const int c  = min(sCntC[ci], SLOTS);
        posCnt[j * CS + sp] = c;
        for (int m = 0; m < c; ++m)
            posS[(j * CS + sp) * SLOTS + m] = sPosC[ci * SLOTS + m];
    }
}

// ---------------- k2: per-row positive terms (atomic-free) -------------------
__global__ __launch_bounds__(256) void k2_pos(const float* __restrict__ denomPart,
                                              const int* __restrict__ posCnt,
                                              const float* __restrict__ posS,
                                              float* __restrict__ termSum,
                                              float* __restrict__ cntF) {
    const int wave = threadIdx.x >> 6;
    const int lane = threadIdx.x & 63;
    const int i    = blockIdx.x * 4 + wave;

    float d  = denomPart[i * CS + lane];
    int   cb = posCnt[i * CS + lane];
    float c  = (float)cb;
#pragma unroll
    for (int off = 32; off; off >>= 1) {
        d += __shfl_xor(d, off);
        c += __shfl_xor(c, off);
    }

    float sum = 0.0f;
    const float* ps = posS + (i * CS + lane) * SLOTS;
    for (int m = 0; m < cb; ++m) {        // divergent; avg ~1 iter, max SLOTS
        float s = ps[m];
        sum += __logf(d + __expf(s)) - s;
    }
#pragma unroll
    for (int off = 32; off; off >>= 1) sum += __shfl_xor(sum, off);
    if (lane == 0) { termSum[i] = sum; cntF[i] = c; }
}

// ---------------- k3: single-block tree reduction ---------------------------
__global__ __launch_bounds__(256) void k3_final(const float* __restrict__ termSum,
                                                const float* __restrict__ cntF,
                                                float* __restrict__ out) {
    __shared__ float sL[256], sC[256];
    float ls = 0.0f, cs = 0.0f;
    for (int i = threadIdx.x; i < B_N; i += 256) { ls += termSum[i]; cs += cntF[i]; }
    sL[threadIdx.x] = ls; sC[threadIdx.x] = cs;
    __syncthreads();
    for (int s = 128; s; s >>= 1) {
        if (threadIdx.x < s) {
            sL[threadIdx.x] += sL[threadIdx.x + s];
            sC[threadIdx.x] += sC[threadIdx.x + s];
        }
        __syncthreads();
    }
    if (threadIdx.x == 0) out[0] = sL[0] / fmaxf(sC[0], 1.0f);
}

extern "C" void kernel_launch(void* const* d_in, const int* in_sizes, int n_in,
                              void* d_out, int out_size, void* d_ws, size_t ws_size,
                              hipStream_t stream) {
    const float* emb    = (const float*)d_in[0];
    const int*   labels = (const int*)d_in[1];
    float*       out    = (float*)d_out;

    char* ws = (char*)d_ws;
    float*         termSum   = (float*)(ws + WS_TERS);
    float*         cntF      = (float*)(ws + WS_CNTF);
    float*         denomPart = (float*)(ws + WS_DENOM);
    int*           posCnt    = (int*)(ws + WS_POSCNT);
    float*         posS      = (float*)(ws + WS_POSS);
    unsigned char* embT8     = (unsigned char*)(ws + WS_EMBT8);

    k0_convert<<<dim3(B_N * D_K / 8 / 256), dim3(256), 0, stream>>>(emb, embT8);

    k1_denom<<<dim3(NTILES), dim3(256), 0, stream>>>(embT8, labels, denomPart, posCnt, posS);

    k2_pos<<<dim3(B_N / 4), dim3(256), 0, stream>>>(denomPart, posCnt, posS, termSum, cntF);

    k3_final<<<dim3(1), dim3(256), 0, stream>>>(termSum, cntF, out);
}

// Round 4
// 101.135 us; speedup vs baseline: 1.0332x; 1.0332x over previous
//
#include <hip/hip_runtime.h>
#include <hip/hip_bf16.h>

// Problem constants (fixed by setup_inputs)
#define B_N 4096
#define D_K 512
#define INV_T 10.0f

// k1 tiling: SYMMETRIC decomposition (see round-1 notes; verified absmax=0).
// Tiles 128 rows x 64 cols; only 2R <= C launched (1056 blocks). Off-diagonal
// tiles feed BOTH row i (row-side reduce) and row j (col-side reduce, two
// 64-row halves -> col-splits 2R, 2R+1). Diagonal super-tiles row-side only.
//
// Round-4 change: k1 register budget. VGPR_Count=64 in R2/R3 proved the
// compiler was NOT keeping the 64-VGPR A-fragment set resident and had no
// headroom for in-flight loads -> latency-serialized (MfmaUtil 0.7%,
// VALUBusy 1.2%, all pipes idle, k1 ~40us regardless of staging strategy).
// Fix: __launch_bounds__(256,2) (cap 256 VGPR) + issue all 16 B-fragment
// loads per col-group before the MFMA chain.
#define BM 128            // rows per block (4 waves x 32 rows)
#define CPB 64            // cols per block
#define CS (B_N / CPB)    // 64 column splits
#define NCG (CPB / 16)    // 4 col-groups per block
#define SLOTS 16          // positive slots per (row, colsplit)
#define NTILES 1056       // sum_{R=0..31} (64 - 2R)

typedef __attribute__((ext_vector_type(4))) float float4v;  // f32x4 accumulator

// ws layout:
//   [0,        16384)    float termSum[4096]
//   [16384,    32768)    float cntF[4096]
//   [32768,  1081344)    float denomPart[4096][64]
//   [1081344,2129920)    int   posCnt[4096][64]
//   [2129920,18907136)   float posS[4096][64][16]
//   [18907136,+2MiB)     fp8   embT8 (fragment order)
#define WS_TERS   0
#define WS_CNTF   16384
#define WS_DENOM  32768
#define WS_POSCNT 1081344
#define WS_POSS   2129920
#define WS_EMBT8  18907136

// ---------------- k0: fp32 -> fp8 e4m3 convert into fragment order -----------
__global__ __launch_bounds__(256) void k0_convert(const float* __restrict__ emb,
                                                  unsigned char* __restrict__ embT8) {
    int tid = blockIdx.x * 256 + threadIdx.x;    // 262144 threads total
    int l16 = tid & 15;
    int kq  = (tid >> 4) & 63;
    int rg  = tid >> 10;
    int row = rg * 16 + l16;
    const float* sp = emb + row * D_K + kq * 8;
    float4 v0 = *(const float4*)(sp);
    float4 v1 = *(const float4*)(sp + 4);
    int lo = __builtin_amdgcn_cvt_pk_fp8_f32(v0.x, v0.y, 0, false);
    lo     = __builtin_amdgcn_cvt_pk_fp8_f32(v0.z, v0.w, lo, true);
    int hi = __builtin_amdgcn_cvt_pk_fp8_f32(v1.x, v1.y, 0, false);
    hi     = __builtin_amdgcn_cvt_pk_fp8_f32(v1.z, v1.w, hi, true);
    int2 o; o.x = lo; o.y = hi;
    *(int2*)(embT8 + ((rg * 64 + kq) * 16 + l16) * 8) = o;
}

// ---------------- k1: symmetric fused sims + denom partials + positives ------
// Barrier-free main loop; A-fragments resident in VGPRs; B-fragments read
// directly from global (embT8 is 8 MB, L2/L3-hot), 16 loads in flight per cg.
__global__ __launch_bounds__(256, 2) void k1_denom(const unsigned char* __restrict__ embT8,
                                                   const int* __restrict__ labels,
                                                   float* __restrict__ denomPart,
                                                   int* __restrict__ posCnt,
                                                   float* __restrict__ posS) {
    __shared__ float sPos[BM * SLOTS];           // row-side positive slots   (8 KB)
    __shared__ int   sCnt[BM];
    __shared__ float sPosC[2 * CPB * SLOTS];     // col-side positive slots   (8 KB)
    __shared__ int   sCntC[2 * CPB];
    __shared__ float sColW[4 * CPB];             // per-wave column partial sums (1 KB)

    const int tid  = threadIdx.x;
    const int wave = tid >> 6;
    const int lane = tid & 63;
    const int quad = lane >> 4;
    const int l16  = lane & 15;

    // Triangular decode: t = R*(65-R) + (C - 2R), C in [2R, 64)
    const int t0 = blockIdx.x;
    int R = (int)((65.0f - sqrtf(4225.0f - 4.0f * (float)t0)) * 0.5f);
    while (R * (65 - R) > t0) --R;
    while ((R + 1) * (64 - R) <= t0) ++R;
    const int C = t0 - R * (65 - R) + 2 * R;
    const bool isDiag = ((C >> 1) == R);
    const int rowBase = R * BM;

    if (tid < BM) sCnt[tid] = 0;
    if (tid < 2 * CPB) sCntC[tid] = 0;
    __syncthreads();   // sCnt/sCntC visible before first positive-pair atomic

    // A fragments: 2 row-groups x 16 K-chunks, 8 B each -> 64 VGPRs, resident
    long afrag[2][16];
#pragma unroll
    for (int t = 0; t < 2; ++t) {
        const int g = R * 8 + wave * 2 + t;
        const unsigned char* ap = embT8 + (g * 1024 + lane) * 8;
#pragma unroll
        for (int kc = 0; kc < 16; ++kc)
            afrag[t][kc] = *(const long*)(ap + kc * 64 * 8);
    }

    int labI[2][4];
#pragma unroll
    for (int t = 0; t < 2; ++t)
#pragma unroll
        for (int r = 0; r < 4; ++r)
            labI[t][r] = labels[rowBase + wave * 32 + t * 16 + quad * 4 + r];

    int labJ[NCG];
#pragma unroll
    for (int cg = 0; cg < NCG; ++cg)
        labJ[cg] = labels[C * CPB + cg * 16 + l16];

    float rowAcc[2][4] = {{0.f,0.f,0.f,0.f},{0.f,0.f,0.f,0.f}};

#pragma unroll
    for (int cg = 0; cg < NCG; ++cg) {
        // B-fragment base for this col-group; per-kc line = btG + kc*512
        const unsigned char* btG = embT8 + (C * NCG + cg) * 8192 + lane * 8;

        // Issue ALL 16 B loads first (32 VGPRs in flight), then the MFMA chain.
        long bfrag[16];
#pragma unroll
        for (int kc = 0; kc < 16; ++kc)
            bfrag[kc] = *(const long*)(btG + kc * 512);

        float4v acc[2];
        acc[0] = (float4v){0.f, 0.f, 0.f, 0.f};
        acc[1] = (float4v){0.f, 0.f, 0.f, 0.f};
#pragma unroll
        for (int kc = 0; kc < 16; ++kc) {
            acc[0] = __builtin_amdgcn_mfma_f32_16x16x32_fp8_fp8(afrag[0][kc], bfrag[kc], acc[0], 0, 0, 0);
            acc[1] = __builtin_amdgcn_mfma_f32_16x16x32_fp8_fp8(afrag[1][kc], bfrag[kc], acc[1], 0, 0, 0);
        }

        const int col = C * CPB + cg * 16 + l16;
        const int lJ  = labJ[cg];
        float cAcc = 0.0f;     // col-side partial (this lane's 8 rows, column `col`)
#pragma unroll
        for (int t = 0; t < 2; ++t) {
#pragma unroll
            for (int r = 0; r < 4; ++r) {
                float s = acc[t][r] * INV_T;
                const int lr = wave * 32 + t * 16 + quad * 4 + r;
                if (lJ != labI[t][r]) {
                    float e = __expf(s);
                    rowAcc[t][r] += e;
                    cAcc += e;
                } else if (col != rowBase + lr) {           // positive pair
                    int idx = atomicAdd(&sCnt[lr], 1);
                    if (idx < SLOTS) sPos[lr * SLOTS + idx] = s;
                    if (!isDiag) {                          // transposed positive (j, i)
                        int ci = (wave >> 1) * CPB + cg * 16 + l16;
                        int idx2 = atomicAdd(&sCntC[ci], 1);
                        if (idx2 < SLOTS) sPosC[ci * SLOTS + idx2] = s;
                    }
                }
            }
        }
        if (!isDiag) {
            // reduce across the 4 quads (rows) -> per-wave column sum
            cAcc += __shfl_xor(cAcc, 16);
            cAcc += __shfl_xor(cAcc, 32);
            if (quad == 0) sColW[wave * CPB + cg * 16 + l16] = cAcc;
        }
    }

    // row-side: butterfly over the 16 l16-lanes -> denomPart[row][C]
#pragma unroll
    for (int t = 0; t < 2; ++t)
#pragma unroll
        for (int r = 0; r < 4; ++r) {
            float v = rowAcc[t][r];
            v += __shfl_xor(v, 1);
            v += __shfl_xor(v, 2);
            v += __shfl_xor(v, 4);
            v += __shfl_xor(v, 8);
            if (l16 == 0)
                denomPart[(rowBase + wave * 32 + t * 16 + quad * 4 + r) * CS + C] = v;
        }

    __syncthreads();   // sPos/sCnt/sPosC/sCntC/sColW complete

    if (tid < BM) {                                   // row-side positive flush
        const int row = rowBase + tid;
        const int c   = min(sCnt[tid], SLOTS);
        posCnt[row * CS + C] = c;
        for (int m = 0; m < c; ++m)
            posS[(row * CS + C) * SLOTS + m] = sPos[tid * SLOTS + m];
    }
    if (!isDiag && tid < 2 * CPB) {                   // col-side flush (transposed cells)
        const int s0 = tid >> 6;                      // which 64-row half -> split 2R+s0
        const int cc = tid & 63;                      // column within block
        const int j  = C * CPB + cc;                  // transposed row index
        const int sp = 2 * R + s0;
        denomPart[j * CS + sp] = sColW[(2 * s0) * CPB + cc] + sColW[(2 * s0 + 1) * CPB + cc];
        const int ci = s0 * CPB + cc;
        const int c  = min(sCntC[ci], SLOTS);
        posCnt[j * CS + sp] = c;
        for (int m = 0; m < c; ++m)
            posS[(j * CS + sp) * SLOTS + m] = sPosC[ci * SLOTS + m];
    }
}

// ---------------- k2: per-row positive terms (atomic-free) -------------------
__global__ __launch_bounds__(256) void k2_pos(const float* __restrict__ denomPart,
                                              const int* __restrict__ posCnt,
                                              const float* __restrict__ posS,
                                              float* __restrict__ termSum,
                                              float* __restrict__ cntF) {
    const int wave = threadIdx.x >> 6;
    const int lane = threadIdx.x & 63;
    const int i    = blockIdx.x * 4 + wave;

    float d  = denomPart[i * CS + lane];
    int   cb = posCnt[i * CS + lane];
    float c  = (float)cb;
#pragma unroll
    for (int off = 32; off; off >>= 1) {
        d += __shfl_xor(d, off);
        c += __shfl_xor(c, off);
    }

    float sum = 0.0f;
    const float* ps = posS + (i * CS + lane) * SLOTS;
    for (int m = 0; m < cb; ++m) {        // divergent; avg ~1 iter, max SLOTS
        float s = ps[m];
        sum += __logf(d + __expf(s)) - s;
    }
#pragma unroll
    for (int off = 32; off; off >>= 1) sum += __shfl_xor(sum, off);
    if (lane == 0) { termSum[i] = sum; cntF[i] = c; }
}

// ---------------- k3: single-block tree reduction ---------------------------
__global__ __launch_bounds__(256) void k3_final(const float* __restrict__ termSum,
                                                const float* __restrict__ cntF,
                                                float* __restrict__ out) {
    __shared__ float sL[256], sC[256];
    float ls = 0.0f, cs = 0.0f;
    for (int i = threadIdx.x; i < B_N; i += 256) { ls += termSum[i]; cs += cntF[i]; }
    sL[threadIdx.x] = ls; sC[threadIdx.x] = cs;
    __syncthreads();
    for (int s = 128; s; s >>= 1) {
        if (threadIdx.x < s) {
            sL[threadIdx.x] += sL[threadIdx.x + s];
            sC[threadIdx.x] += sC[threadIdx.x + s];
        }
        __syncthreads();
    }
    if (threadIdx.x == 0) out[0] = sL[0] / fmaxf(sC[0], 1.0f);
}

extern "C" void kernel_launch(void* const* d_in, const int* in_sizes, int n_in,
                              void* d_out, int out_size, void* d_ws, size_t ws_size,
                              hipStream_t stream) {
    const float* emb    = (const float*)d_in[0];
    const int*   labels = (const int*)d_in[1];
    float*       out    = (float*)d_out;

    char* ws = (char*)d_ws;
    float*         termSum   = (float*)(ws + WS_TERS);
    float*         cntF      = (float*)(ws + WS_CNTF);
    float*         denomPart = (float*)(ws + WS_DENOM);
    int*           posCnt    = (int*)(ws + WS_POSCNT);
    float*         posS      = (float*)(ws + WS_POSS);
    unsigned char* embT8     = (unsigned char*)(ws + WS_EMBT8);

    k0_convert<<<dim3(B_N * D_K / 8 / 256), dim3(256), 0, stream>>>(emb, embT8);

    k1_denom<<<dim3(NTILES), dim3(256), 0, stream>>>(embT8, labels, denomPart, posCnt, posS);

    k2_pos<<<dim3(B_N / 4), dim3(256), 0, stream>>>(denomPart, posCnt, posS, termSum, cntF);

    k3_final<<<dim3(1), dim3(256), 0, stream>>>(termSum, cntF, out);
}

// Round 5
// 98.010 us; speedup vs baseline: 1.0661x; 1.0319x over previous
//
#include <hip/hip_runtime.h>
#include <hip/hip_bf16.h>

// Problem constants (fixed by setup_inputs)
#define B_N 4096
#define D_K 512
#define INV_T 10.0f

// k1: SYMMETRIC decomposition at FULL 128x128 super-tiles.
// Round-5 analysis: k1 was ~39us in ALL prior variants. 64-wide symmetric
// tiles halved FLOPs but doubled per-MFMA overhead (A-panel load, prologue,
// epilogue, flush amortized over half the math) -> net zero vs full matrix.
// Fix: keep symmetric halving, restore 128-wide tiles: 528 blocks (C >= R),
// ~2 blocks/CU fully co-resident at launch_bounds(256,2).
//   - off-diag tile (R,C): row-side reduce for rows i in R-panel (slot 2C,
//     zero written at 2C+1), col-side reduce for rows j in C-panel over the
//     two 64-row i-halves -> slots 2R, 2R+1.  Diagonal (C==R): row-side only
//     with self-exclusion.
//   - coverage per (row i, slot s): col-side covers s in [0, 2*(i>>7)),
//     row-side covers evens in [2*(i>>7), 64) + zeroed odds. Exactly-once.
#define BM 128            // rows per block (4 waves x 32 rows)
#define CPB 128           // cols per block
#define CS 64             // 64 column-split slots per row (64-col granularity)
#define NCG (CPB / 16)    // 8 col-groups per block
#define SLOTS 16          // positive slots per (row, slot); row-side mean 2, col-side mean 1
#define NTILES 528        // 32*33/2 upper-triangle super-tiles

typedef __attribute__((ext_vector_type(4))) float float4v;  // f32x4 accumulator

// ws layout:
//   [0,        16384)    float termSum[4096]
//   [16384,    32768)    float cntF[4096]
//   [32768,  1081344)    float denomPart[4096][64]
//   [1081344,2129920)    int   posCnt[4096][64]
//   [2129920,18907136)   float posS[4096][64][16]
//   [18907136,+2MiB)     fp8   embT8 (fragment order)
#define WS_TERS   0
#define WS_CNTF   16384
#define WS_DENOM  32768
#define WS_POSCNT 1081344
#define WS_POSS   2129920
#define WS_EMBT8  18907136

// ---------------- k0: fp32 -> fp8 e4m3 convert into fragment order -----------
__global__ __launch_bounds__(256) void k0_convert(const float* __restrict__ emb,
                                                  unsigned char* __restrict__ embT8) {
    int tid = blockIdx.x * 256 + threadIdx.x;    // 262144 threads total
    int l16 = tid & 15;
    int kq  = (tid >> 4) & 63;
    int rg  = tid >> 10;
    int row = rg * 16 + l16;
    const float* sp = emb + row * D_K + kq * 8;
    float4 v0 = *(const float4*)(sp);
    float4 v1 = *(const float4*)(sp + 4);
    int lo = __builtin_amdgcn_cvt_pk_fp8_f32(v0.x, v0.y, 0, false);
    lo     = __builtin_amdgcn_cvt_pk_fp8_f32(v0.z, v0.w, lo, true);
    int hi = __builtin_amdgcn_cvt_pk_fp8_f32(v1.x, v1.y, 0, false);
    hi     = __builtin_amdgcn_cvt_pk_fp8_f32(v1.z, v1.w, hi, true);
    int2 o; o.x = lo; o.y = hi;
    *(int2*)(embT8 + ((rg * 64 + kq) * 16 + l16) * 8) = o;
}

// ---------------- k1: symmetric fused sims + denom partials + positives ------
// Barrier-free main loop; A-fragments resident; B-fragments batched direct
// from global (embT8 = 8 MB, L2/L3-hot).
__global__ __launch_bounds__(256, 2) void k1_denom(const unsigned char* __restrict__ embT8,
                                                   const int* __restrict__ labels,
                                                   float* __restrict__ denomPart,
                                                   int* __restrict__ posCnt,
                                                   float* __restrict__ posS) {
    __shared__ float sPos[BM * SLOTS];           // row-side positive slots   (8 KB)
    __shared__ int   sCnt[BM];
    __shared__ float sPosC[2 * CPB * SLOTS];     // col-side positive slots  (16 KB)
    __shared__ int   sCntC[2 * CPB];
    __shared__ float sColW[4 * CPB];             // per-wave column partial sums (2 KB)

    const int tid  = threadIdx.x;
    const int wave = tid >> 6;
    const int lane = tid & 63;
    const int quad = lane >> 4;
    const int l16  = lane & 15;

    // Triangular decode: tile t0 -> (R, C), C in [R, 32). Linear SALU scan.
    const int t0 = blockIdx.x;
    int R = 0, accT = 0;
    while (accT + (32 - R) <= t0) { accT += 32 - R; ++R; }
    const int C = R + (t0 - accT);
    const bool isDiag = (C == R);
    const int rowBase = R * BM;

    if (tid < BM) sCnt[tid] = 0;
    sCntC[tid] = 0;                              // 2*CPB == 256 == blockDim
    __syncthreads();   // counters visible before first positive-pair atomic

    // A fragments: 2 row-groups x 16 K-chunks, 8 B each -> 64 VGPRs, resident
    long afrag[2][16];
#pragma unroll
    for (int t = 0; t < 2; ++t) {
        const int g = R * 8 + wave * 2 + t;
        const unsigned char* ap = embT8 + (g * 1024 + lane) * 8;
#pragma unroll
        for (int kc = 0; kc < 16; ++kc)
            afrag[t][kc] = *(const long*)(ap + kc * 64 * 8);
    }

    int labI[2][4];
#pragma unroll
    for (int t = 0; t < 2; ++t)
#pragma unroll
        for (int r = 0; r < 4; ++r)
            labI[t][r] = labels[rowBase + wave * 32 + t * 16 + quad * 4 + r];

    int labJ[NCG];
#pragma unroll
    for (int cg = 0; cg < NCG; ++cg)
        labJ[cg] = labels[C * CPB + cg * 16 + l16];

    float rowAcc[2][4] = {{0.f,0.f,0.f,0.f},{0.f,0.f,0.f,0.f}};

#pragma unroll
    for (int cg = 0; cg < NCG; ++cg) {
        // B-fragment base for this col-group; per-kc line = btG + kc*512
        const unsigned char* btG = embT8 + (C * NCG + cg) * 8192 + lane * 8;

        // Issue ALL 16 B loads first (32 VGPRs in flight), then the MFMA chain.
        long bfrag[16];
#pragma unroll
        for (int kc = 0; kc < 16; ++kc)
            bfrag[kc] = *(const long*)(btG + kc * 512);

        float4v acc[2];
        acc[0] = (float4v){0.f, 0.f, 0.f, 0.f};
        acc[1] = (float4v){0.f, 0.f, 0.f, 0.f};
#pragma unroll
        for (int kc = 0; kc < 16; ++kc) {
            acc[0] = __builtin_amdgcn_mfma_f32_16x16x32_fp8_fp8(afrag[0][kc], bfrag[kc], acc[0], 0, 0, 0);
            acc[1] = __builtin_amdgcn_mfma_f32_16x16x32_fp8_fp8(afrag[1][kc], bfrag[kc], acc[1], 0, 0, 0);
        }

        const int col = C * CPB + cg * 16 + l16;
        const int lJ  = labJ[cg];
        float cAcc = 0.0f;     // col-side partial (this lane's 8 rows, column `col`)
#pragma unroll
        for (int t = 0; t < 2; ++t) {
#pragma unroll
            for (int r = 0; r < 4; ++r) {
                float s = acc[t][r] * INV_T;
                const int lr = wave * 32 + t * 16 + quad * 4 + r;
                if (lJ != labI[t][r]) {
                    float e = __expf(s);
                    rowAcc[t][r] += e;
                    cAcc += e;
                } else if (col != rowBase + lr) {           // positive pair
                    int idx = atomicAdd(&sCnt[lr], 1);
                    if (idx < SLOTS) sPos[lr * SLOTS + idx] = s;
                    if (!isDiag) {                          // transposed positive (j, i)
                        int ci = (wave >> 1) * CPB + cg * 16 + l16;
                        int idx2 = atomicAdd(&sCntC[ci], 1);
                        if (idx2 < SLOTS) sPosC[ci * SLOTS + idx2] = s;
                    }
                }
            }
        }
        if (!isDiag) {
            // reduce across the 4 quads (rows) -> per-wave column sum
            cAcc += __shfl_xor(cAcc, 16);
            cAcc += __shfl_xor(cAcc, 32);
            if (quad == 0) sColW[wave * CPB + cg * 16 + l16] = cAcc;
        }
    }

    // row-side: butterfly over the 16 l16-lanes -> denomPart[row][2C] (+zero odd)
#pragma unroll
    for (int t = 0; t < 2; ++t)
#pragma unroll
        for (int r = 0; r < 4; ++r) {
            float v = rowAcc[t][r];
            v += __shfl_xor(v, 1);
            v += __shfl_xor(v, 2);
            v += __shfl_xor(v, 4);
            v += __shfl_xor(v, 8);
            if (l16 == 0) {
                const int row = rowBase + wave * 32 + t * 16 + quad * 4 + r;
                denomPart[row * CS + 2 * C]     = v;
                denomPart[row * CS + 2 * C + 1] = 0.0f;
            }
        }

    __syncthreads();   // sPos/sCnt/sPosC/sCntC/sColW complete

    if (tid < BM) {                                   // row-side positive flush
        const int row = rowBase + tid;
        const int c   = min(sCnt[tid], SLOTS);
        posCnt[row * CS + 2 * C]     = c;
        posCnt[row * CS + 2 * C + 1] = 0;
        for (int m = 0; m < c; ++m)
            posS[(row * CS + 2 * C) * SLOTS + m] = sPos[tid * SLOTS + m];
    }
    if (!isDiag) {                                    // col-side flush (all 256 threads)
        const int s0 = tid >> 7;                      // which 64-row i-half -> slot 2R+s0
        const int cc = tid & (CPB - 1);               // column within tile
        const int j  = C * CPB + cc;                  // transposed row index
        const int sp = 2 * R + s0;
        denomPart[j * CS + sp] = sColW[(2 * s0) * CPB + cc] + sColW[(2 * s0 + 1) * CPB + cc];
        const int ci = s0 * CPB + cc;
        const int c  = min(sCntC[ci], SLOTS);
        posCnt[j * CS + sp] = c;
        for (int m = 0; m < c; ++m)
            posS[(j * CS + sp) * SLOTS + m] = sPosC[ci * SLOTS + m];
    }
}

// ---------------- k2: per-row positive terms (atomic-free) -------------------
__global__ __launch_bounds__(256) void k2_pos(const float* __restrict__ denomPart,
                                              const int* __restrict__ posCnt,
                                              const float* __restrict__ posS,
                                              float* __restrict__ termSum,
                                              float* __restrict__ cntF) {
    const int wave = threadIdx.x >> 6;
    const int lane = threadIdx.x & 63;
    const int i    = blockIdx.x * 4 + wave;

    float d  = denomPart[i * CS + lane];
    int   cb = posCnt[i * CS + lane];
    float c  = (float)cb;
#pragma unroll
    for (int off = 32; off; off >>= 1) {
        d += __shfl_xor(d, off);
        c += __shfl_xor(c, off);
    }

    float sum = 0.0f;
    const float* ps = posS + (i * CS + lane) * SLOTS;
    for (int m = 0; m < cb; ++m) {        // divergent; avg ~1 iter, max SLOTS
        float s = ps[m];
        sum += __logf(d + __expf(s)) - s;
    }
#pragma unroll
    for (int off = 32; off; off >>= 1) sum += __shfl_xor(sum, off);
    if (lane == 0) { termSum[i] = sum; cntF[i] = c; }
}

// ---------------- k3: single-block tree reduction ---------------------------
__global__ __launch_bounds__(256) void k3_final(const float* __restrict__ termSum,
                                                const float* __restrict__ cntF,
                                                float* __restrict__ out) {
    __shared__ float sL[256], sC[256];
    float ls = 0.0f, cs = 0.0f;
    for (int i = threadIdx.x; i < B_N; i += 256) { ls += termSum[i]; cs += cntF[i]; }
    sL[threadIdx.x] = ls; sC[threadIdx.x] = cs;
    __syncthreads();
    for (int s = 128; s; s >>= 1) {
        if (threadIdx.x < s) {
            sL[threadIdx.x] += sL[threadIdx.x + s];
            sC[threadIdx.x] += sC[threadIdx.x + s];
        }
        __syncthreads();
    }
    if (threadIdx.x == 0) out[0] = sL[0] / fmaxf(sC[0], 1.0f);
}

extern "C" void kernel_launch(void* const* d_in, const int* in_sizes, int n_in,
                              void* d_out, int out_size, void* d_ws, size_t ws_size,
                              hipStream_t stream) {
    const float* emb    = (const float*)d_in[0];
    const int*   labels = (const int*)d_in[1];
    float*       out    = (float*)d_out;

    char* ws = (char*)d_ws;
    float*         termSum   = (float*)(ws + WS_TERS);
    float*         cntF      = (float*)(ws + WS_CNTF);
    float*         denomPart = (float*)(ws + WS_DENOM);
    int*           posCnt    = (int*)(ws + WS_POSCNT);
    float*         posS      = (float*)(ws + WS_POSS);
    unsigned char* embT8     = (unsigned char*)(ws + WS_EMBT8);

    k0_convert<<<dim3(B_N * D_K / 8 / 256), dim3(256), 0, stream>>>(emb, embT8);

    k1_denom<<<dim3(NTILES), dim3(256), 0, stream>>>(embT8, labels, denomPart, posCnt, posS);

    k2_pos<<<dim3(B_N / 4), dim3(256), 0, stream>>>(denomPart, posCnt, posS, termSum, cntF);

    k3_final<<<dim3(1), dim3(256), 0, stream>>>(termSum, cntF, out);
}